// Round 3
// baseline (152.106 us; speedup 1.0000x reference)
//
#include <hip/hip_runtime.h>
#include <math.h>

// CenterNetDecode: heat [8,80,192,192] f32, box [8,4,192,192] f32
// outputs (flat concat): boxes [B,H,W,4], mask [B,H,W], scores [B,H,W], center [B,H,W,2]
//
// Single fused kernel. Block = one 8-row strip of one batch image, all 80
// channels (4 waves x 20 channels), so no cross-block partials and no second
// launch. Wave = full image row: lanes 0..47 hold float4 (cols 4l..4l+3);
// vertical 3-max in regs, horizontal 3-max via 2 shuffles/row; LDS reduce of
// the 4 channel-group planes; decode epilogue inline.

#define BB 8
#define CC 80
#define HH 192
#define WW 192
#define SS 8                 // output rows per block strip
#define NB (HH*WW)
#define NBPIX (BB*NB)        // 294912

__global__ __launch_bounds__(256) void fused_kernel(const float* __restrict__ heat,
                                                    const float* __restrict__ box,
                                                    float* __restrict__ out) {
    const int tid  = threadIdx.x;
    const int lane = tid & 63;
    const int wv   = tid >> 6;        // wave 0..3 -> channels wv*20..wv*20+19
    const int yt   = blockIdx.x;      // 0..23
    const int b    = blockIdx.y;      // 0..7
    const int y0   = yt * SS;
    const bool lok = lane < 48;
    const int  col0 = lane * 4;

    __shared__ float red[4][SS][WW];  // 24 KB

    float4 sc[SS];
#pragma unroll
    for (int i = 0; i < SS; ++i) sc[i] = make_float4(0.f, 0.f, 0.f, 0.f);

    const float NI = -INFINITY;

    for (int k = 0; k < 20; ++k) {
        const int c = wv * 20 + k;
        const float* hp = heat + ((size_t)(b * CC + c) * HH) * WW;
        float4 v[SS + 2];
#pragma unroll
        for (int r = 0; r < SS + 2; ++r) {
            const int  row = y0 - 1 + r;
            const bool ok  = lok && ((unsigned)row < HH);
            v[r] = ok ? *reinterpret_cast<const float4*>(hp + row * WW + col0)
                      : make_float4(NI, NI, NI, NI);
        }
#pragma unroll
        for (int i = 0; i < SS; ++i) {
            const float4 a = v[i], m = v[i + 1], d = v[i + 2];
            float4 vm;
            vm.x = fmaxf(fmaxf(a.x, m.x), d.x);
            vm.y = fmaxf(fmaxf(a.y, m.y), d.y);
            vm.z = fmaxf(fmaxf(a.z, m.z), d.z);
            vm.w = fmaxf(fmaxf(a.w, m.w), d.w);

            float L = __shfl_up(vm.w, 1);    // left neighbor's col (4l-1)
            float R = __shfl_down(vm.x, 1);  // right neighbor's col (4l+4)
            if (lane == 0)  L = NI;          // image left edge
            if (lane >= 47) R = NI;          // image right edge / inactive

            float4 hm;
            hm.x = fmaxf(fmaxf(L,    vm.x), vm.y);
            hm.y = fmaxf(fmaxf(vm.x, vm.y), vm.z);
            hm.z = fmaxf(fmaxf(vm.y, vm.z), vm.w);
            hm.w = fmaxf(fmaxf(vm.z, vm.w), R);

            sc[i].x = fmaxf(sc[i].x, (m.x == hm.x) ? m.x : 0.0f);
            sc[i].y = fmaxf(sc[i].y, (m.y == hm.y) ? m.y : 0.0f);
            sc[i].z = fmaxf(sc[i].z, (m.z == hm.z) ? m.z : 0.0f);
            sc[i].w = fmaxf(sc[i].w, (m.w == hm.w) ? m.w : 0.0f);
        }
    }

    if (lok) {
#pragma unroll
        for (int i = 0; i < SS; ++i)
            *reinterpret_cast<float4*>(&red[wv][i][col0]) = sc[i];
    }
    __syncthreads();

    // Decode epilogue: 1536 pixels per block, 6 per thread.
    float* boxes  = out;
    float* maskp  = out + (size_t)4 * NBPIX;
    float* scorep = out + (size_t)5 * NBPIX;
    float* ctr    = out + (size_t)6 * NBPIX;

#pragma unroll
    for (int k = 0; k < SS * WW / 256; ++k) {   // 6 iters
        const int idx = k * 256 + tid;
        const int row = idx / WW, col = idx - row * WW;
        const float s = fmaxf(fmaxf(red[0][row][col], red[1][row][col]),
                              fmaxf(red[2][row][col], red[3][row][col]));
        const bool  m = s > 0.7f;

        const int y   = y0 + row;
        const int rem = y * WW + col;
        const int pix = b * NB + rem;

        const float* bp = box + (size_t)b * 4 * NB + rem;
        const float dx = bp[0];
        const float dy = bp[NB];
        const float bw = bp[2 * NB];
        const float bh = bp[3 * NB];

        const float cx = ((float)col + dx) * 4.0f;
        const float cy = ((float)y   + dy) * 4.0f;
        const float w4 = bw * 4.0f;
        const float h4 = bh * 4.0f;
        const float lim = 768.0f;
        const float x1 = fminf(fmaxf(cx - w4 * 0.5f, 0.0f), lim);
        const float y1 = fminf(fmaxf(cy - h4 * 0.5f, 0.0f), lim);
        const float x2 = fminf(fmaxf(cx + w4 * 0.5f, 0.0f), lim);
        const float y2 = fminf(fmaxf(cy + h4 * 0.5f, 0.0f), lim);

        float4 bo;
        bo.x = m ? x1 : 0.0f;
        bo.y = m ? y1 : 0.0f;
        bo.z = m ? (x2 - x1) : 0.0f;
        bo.w = m ? (y2 - y1) : 0.0f;
        reinterpret_cast<float4*>(boxes)[pix] = bo;

        maskp[pix]  = m ? 1.0f : 0.0f;
        scorep[pix] = m ? s : 0.0f;

        float2 cc;
        cc.x = m ? cx : 0.0f;
        cc.y = m ? cy : 0.0f;
        reinterpret_cast<float2*>(ctr)[pix] = cc;
    }
}

extern "C" void kernel_launch(void* const* d_in, const int* in_sizes, int n_in,
                              void* d_out, int out_size, void* d_ws, size_t ws_size,
                              hipStream_t stream) {
    const float* heat = (const float*)d_in[0];
    const float* box  = (const float*)d_in[1];
    float* out = (float*)d_out;

    dim3 g(HH / SS, BB);            // 24 x 8 = 192 blocks
    fused_kernel<<<g, 256, 0, stream>>>(heat, box, out);
}